// Round 11
// baseline (106.843 us; speedup 1.0000x reference)
//
#include <hip/hip_runtime.h>

// WaveKANLinear: out[n,o] = sum_d mexhat((ln(x)[n,d]-t[o,d])/s[o,d]) * ww[o,d]
//                           + silu(sum_d x[n,d]*bw[o,d])
// N=8192, D=128, O=128, float32 in/out.
// R11 == R10 resubmitted (R10 bench died to container infra, no signal).
// R10: 4 blocks/CU x 8 waves = 32 waves/CU (8/SIMD) WITH LDS-resident weights.
//   block = 32 o x 32 rows, BLOCK=512, grid=1024, LDS = exactly 40960 B:
//     s_w  [128 d][32 o] uint2 {bf16(tis'|isv), bf16(wwk|bwg)}  32 KB
//     s_ln [16 rowpair][128 d] uint {bf16 ln' row2k | row2k+1}    8 KB
//   tis' = (beta - t)*isv and ln' = (v-mean)*rstd*gamma  (beta folds away;
//   base = sv*accb + mean*sb, sb[o]=sum bw read from global at epilogue).
//   mean/sv stay in REGISTERS, fetched at epilogue via __shfl. Hot loop:
//   barrier-free, global-free, conflict-free.

#define D_DIM 128
#define O_DIM 128
#define ROWS  32     // rows per block
#define BLOCK 512    // 8 waves; lane = o(32) + 32*ph; thread = 2 rows
#define OQ    32     // outputs per block (o-quarter)

#define C1     0.72134752f   // 0.5*log2(e); exp(-z^2/2) = exp2(-C1*z^2)
#define SQRT_C 0.84932180f   // sqrt(C1)
#define WWK    1.2023651f    // MEX_C / C1, MEX_C = 2/(sqrt(3)*pi^0.25)
#define LOG2E  1.44269504f

__device__ __forceinline__ unsigned bf16r(float f) {   // RNE round to bf16 bits
    unsigned u = __float_as_uint(f);
    return (u + 0x7fffu + ((u >> 16) & 1u)) >> 16;
}

// Prep1: table [d][o] uint2 { bf16(tis'|isv), bf16(wwk|bwg) }
//   tis' = (beta[d] - trans)*isv  (so u = ln'*isv + tis'), bwg = bw/gamma.
__global__ __launch_bounds__(256) void wavekan_prep(
    const float* __restrict__ scale,
    const float* __restrict__ trans,
    const float* __restrict__ ww,
    const float* __restrict__ bw,
    const float* __restrict__ gamma,
    const float* __restrict__ beta,
    uint2* __restrict__ wsW)
{
    int idx = blockIdx.x * blockDim.x + threadIdx.x;   // = o*128 + d
    if (idx >= O_DIM * D_DIM) return;
    int o = idx >> 7;
    int d = idx & (D_DIM - 1);
    float sc = scale[idx];
    float sp = fmaxf(sc, 0.0f) + log1pf(__expf(-fabsf(sc)));  // stable softplus
    float is2 = SQRT_C / (sp + 0.1f);
    float tis2 = (beta[d] - trans[idx]) * is2;
    float bwg = bw[idx] / gamma[d];
    uint2 w;
    w.x = bf16r(tis2)          | (bf16r(is2) << 16);
    w.y = bf16r(ww[idx] * WWK) | (bf16r(bwg) << 16);
    wsW[d * O_DIM + o] = w;
}

// Prep2: sb[o] = sum_d bw[o][d]
__global__ __launch_bounds__(128) void wavekan_prep2(
    const float* __restrict__ bw,
    float* __restrict__ sb)
{
    int o = blockIdx.x, t = threadIdx.x;
    float s = bw[o * D_DIM + t];
    #pragma unroll
    for (int m = 1; m < 64; m <<= 1) s += __shfl_xor(s, m, 64);
    __shared__ float tmp[2];
    if ((t & 63) == 0) tmp[t >> 6] = s;
    __syncthreads();
    if (t == 0) sb[o] = tmp[0] + tmp[1];
}

__global__ __launch_bounds__(BLOCK, 8) void wavekan_main(
    const float* __restrict__ x,
    const uint2* __restrict__ wsW,
    const float* __restrict__ sb,
    const float* __restrict__ gamma,
    float* __restrict__ out,
    int N)
{
    __shared__ uint2 s_w[D_DIM * OQ];     // 32768 B
    __shared__ unsigned s_ln[16 * D_DIM]; //  8192 B   (total 40960 = 160K/4)

    const int tid  = threadIdx.x;
    const int q    = blockIdx.x & 3;               // o-quarter
    const int row0 = (blockIdx.x >> 2) * ROWS;

    // ---- Phase 0: stage o-quarter of weight table (32 KB) ----
    {
        const uint4* wsW4 = reinterpret_cast<const uint4*>(wsW);
        uint4* sw4 = reinterpret_cast<uint4*>(s_w);
        #pragma unroll
        for (int k = 0; k < 4; ++k) {
            int flat = tid + k * BLOCK;            // 0..2047
            int d = flat >> 4, i = flat & 15;
            sw4[flat] = wsW4[d * 64 + q * 16 + i];
        }
    }

    // ---- Phase 1: 32 rows, 16 lanes/row x 8 elems; LayerNorm -> bf16 LDS ----
    float mean, sv;
    {
        const int r  = tid >> 4;                   // row 0..31
        const int j  = tid & 15;
        const int d0 = j * 8;
        const int grow = row0 + r;

        float v[8];
        if (grow < N) {
            const float4* p = reinterpret_cast<const float4*>(x + (size_t)grow * D_DIM + d0);
            float4 a = p[0], b4 = p[1];
            v[0]=a.x; v[1]=a.y; v[2]=a.z; v[3]=a.w;
            v[4]=b4.x; v[5]=b4.y; v[6]=b4.z; v[7]=b4.w;
        } else {
            #pragma unroll
            for (int k = 0; k < 8; ++k) v[k] = 0.0f;
        }
        float sum = 0.f, ssq = 0.f;
        #pragma unroll
        for (int k = 0; k < 8; ++k) { sum += v[k]; ssq += v[k] * v[k]; }
        #pragma unroll
        for (int m = 1; m < 16; m <<= 1) {
            sum += __shfl_xor(sum, m, 64);
            ssq += __shfl_xor(ssq, m, 64);
        }
        mean = sum * (1.0f / D_DIM);
        const float var  = ssq * (1.0f / D_DIM) - mean * mean;
        const float rstd = rsqrtf(var + 1e-5f);
        sv = (var + 1e-5f) * rstd;                 // sqrt(var+eps)

        const float4* pg = reinterpret_cast<const float4*>(gamma + d0);
        float4 g0 = pg[0], g1 = pg[1];
        float gg[8] = {g0.x,g0.y,g0.z,g0.w,g1.x,g1.y,g1.z,g1.w};

        // ln' = (v-mean)*rstd*gamma (beta folded into table)
        unsigned short* sl = reinterpret_cast<unsigned short*>(s_ln);
        const int pr  = r >> 1;                    // row-pair 0..15
        const int hlf = r & 1;
        #pragma unroll
        for (int k = 0; k < 8; ++k) {
            float ln = (v[k] - mean) * rstd * gg[k];
            sl[(pr * D_DIM + d0 + k) * 2 + hlf] = (unsigned short)bf16r(ln);
        }
    }
    __syncthreads();   // the ONLY barrier

    // ---- Phase 2: lane = o + 32*ph; thread rows {4g+2ph, 4g+2ph+1} ----
    const int lane = tid & 63;
    const int g    = tid >> 6;                     // wave 0..7
    const int ol   = lane & 31;
    const int ph   = lane >> 5;
    const int kpr  = 2 * g + ph;                   // row-pair index

    float accw0 = 0.f, accw1 = 0.f, accb0 = 0.f, accb1 = 0.f;

    #pragma unroll 4
    for (int d = 0; d < D_DIM; ++d) {
        uint2 wv    = s_w[d * OQ + ol];            // b64, 2-way broadcast, conflict-free
        unsigned xv = s_ln[kpr * D_DIM + d];       // b32, half-wave uniform
        float tis = __uint_as_float(wv.x << 16);
        float isv = __uint_as_float(wv.x & 0xffff0000u);
        float wwk = __uint_as_float(wv.y << 16);
        float bwg = __uint_as_float(wv.y & 0xffff0000u);
        float x0  = __uint_as_float(xv << 16);
        float x1  = __uint_as_float(xv & 0xffff0000u);

        float u0 = fmaf(x0, isv, tis);
        float u1 = fmaf(x1, isv, tis);
        float q0 = u0 * u0, q1 = u1 * u1;
        float e0 = __builtin_amdgcn_exp2f(-q0);
        float e1 = __builtin_amdgcn_exp2f(-q1);
        float wc = wwk * (-C1);
        float p0 = fmaf(q0, wwk, wc);
        float p1 = fmaf(q1, wwk, wc);
        accw0 = fmaf(p0, e0, accw0);
        accw1 = fmaf(p1, e1, accw1);
        accb0 = fmaf(x0, bwg, accb0);
        accb1 = fmaf(x1, bwg, accb1);
    }

    // ---- Epilogue: mean/sv via intra-wave shuffle; base = sv*accb + mean*sb ----
    {
        const int og  = q * OQ + ol;               // global o
        const float sbv = sb[og];
        float m0 = __shfl(mean, ph * 32,      64);
        float s0 = __shfl(sv,   ph * 32,      64);
        float m1 = __shfl(mean, ph * 32 + 16, 64);
        float s1 = __shfl(sv,   ph * 32 + 16, 64);
        const int r0 = row0 + 4 * g + 2 * ph;
        if (r0 < N) {
            float base = fmaf(s0, accb0, m0 * sbv);
            float sig  = 1.0f / (1.0f + __builtin_amdgcn_exp2f(-LOG2E * base));
            out[(size_t)r0 * O_DIM + og] = accw0 + base * sig;
        }
        if (r0 + 1 < N) {
            float base = fmaf(s1, accb1, m1 * sbv);
            float sig  = 1.0f / (1.0f + __builtin_amdgcn_exp2f(-LOG2E * base));
            out[(size_t)(r0 + 1) * O_DIM + og] = accw1 + base * sig;
        }
    }
}

// Fallback (no workspace): correctness-only.
__global__ __launch_bounds__(1024, 8) void wavekan_main_fb(
    const float* __restrict__ x,
    const float* __restrict__ scale,
    const float* __restrict__ trans,
    const float* __restrict__ ww,
    const float* __restrict__ bw,
    const float* __restrict__ gamma,
    const float* __restrict__ beta,
    float* __restrict__ out,
    int N)
{
    __shared__ float4 s_x[128 * 9];
    const int tid = threadIdx.x;
    const int row0 = blockIdx.x * 16;
    {
        const int r = tid >> 6, j = tid & 63, d0 = j * 2;
        const int grow = row0 + r;
        float2 v2 = make_float2(0.f, 0.f);
        if (grow < N) v2 = *reinterpret_cast<const float2*>(x + (size_t)grow * D_DIM + d0);
        float sum = v2.x + v2.y, ssq = v2.x * v2.x + v2.y * v2.y;
        #pragma unroll
        for (int m = 1; m < 64; m <<= 1) { sum += __shfl_xor(sum, m, 64); ssq += __shfl_xor(ssq, m, 64); }
        const float mean = sum / 128.f, var = ssq / 128.f - mean * mean;
        const float rstd = rsqrtf(var + 1e-5f);
        float2 g2 = *reinterpret_cast<const float2*>(gamma + d0);
        float2 b2 = *reinterpret_cast<const float2*>(beta + d0);
        const int p = r >> 1, hh = r & 1;
        float* c0 = reinterpret_cast<float*>(&s_x[d0 * 9 + p]);
        float* c1 = reinterpret_cast<float*>(&s_x[(d0 + 1) * 9 + p]);
        c0[hh] = (v2.x - mean) * rstd * g2.x + b2.x; c0[2 + hh] = v2.x;
        c1[hh] = (v2.y - mean) * rstd * g2.y + b2.y; c1[2 + hh] = v2.y;
    }
    __syncthreads();
    const int o = tid & 127, g = tid >> 7;
    float aw0 = 0.f, aw1 = 0.f, ab0 = 0.f, ab1 = 0.f;
    for (int d = 0; d < D_DIM; ++d) {
        int idx = o * D_DIM + d;
        float sc = scale[idx];
        float sp = fmaxf(sc, 0.0f) + log1pf(__expf(-fabsf(sc)));
        float is = SQRT_C / (sp + 0.1f);
        float tws = trans[idx] * is, wwk = ww[idx] * WWK, bwv = bw[idx];
        float4 xx = s_x[d * 9 + g];
        float u0 = fmaf(xx.x, is, -tws), u1 = fmaf(xx.y, is, -tws);
        float q0 = u0 * u0, q1 = u1 * u1;
        aw0 = fmaf((q0 - C1) * __builtin_amdgcn_exp2f(-q0), wwk, aw0);
        aw1 = fmaf((q1 - C1) * __builtin_amdgcn_exp2f(-q1), wwk, aw1);
        ab0 = fmaf(xx.z, bwv, ab0);
        ab1 = fmaf(xx.w, bwv, ab1);
    }
    const int rr0 = row0 + g * 2;
    if (rr0 < N) {
        float s0 = 1.0f / (1.0f + __builtin_amdgcn_exp2f(-LOG2E * ab0));
        out[(size_t)rr0 * O_DIM + o] = aw0 + ab0 * s0;
    }
    if (rr0 + 1 < N) {
        float s1 = 1.0f / (1.0f + __builtin_amdgcn_exp2f(-LOG2E * ab1));
        out[(size_t)(rr0 + 1) * O_DIM + o] = aw1 + ab1 * s1;
    }
}

extern "C" void kernel_launch(void* const* d_in, const int* in_sizes, int n_in,
                              void* d_out, int out_size, void* d_ws, size_t ws_size,
                              hipStream_t stream) {
    const float* x     = (const float*)d_in[0];
    const float* scale = (const float*)d_in[1];
    const float* trans = (const float*)d_in[2];
    const float* ww    = (const float*)d_in[3];
    const float* bw    = (const float*)d_in[4];
    const float* gamma = (const float*)d_in[5];
    const float* beta  = (const float*)d_in[6];
    float* out = (float*)d_out;

    const int N = in_sizes[0] / D_DIM;       // 8192

    const size_t tbl_bytes = (size_t)O_DIM * D_DIM * sizeof(uint2);   // 128 KB
    const size_t ws_needed = tbl_bytes + O_DIM * sizeof(float);
    if (ws_size >= ws_needed) {
        uint2* tbl = (uint2*)d_ws;
        float* sbp = (float*)((char*)d_ws + tbl_bytes);
        wavekan_prep<<<(O_DIM * D_DIM + 255) / 256, 256, 0, stream>>>(
            scale, trans, ww, bw, gamma, beta, tbl);
        wavekan_prep2<<<O_DIM, 128, 0, stream>>>(bw, sbp);
        const int grid = ((N + ROWS - 1) / ROWS) * 4;   // 1024
        wavekan_main<<<grid, BLOCK, 0, stream>>>(
            x, tbl, sbp, gamma, out, N);
    } else {
        wavekan_main_fb<<<(N + 15) / 16, 1024, 0, stream>>>(
            x, scale, trans, ww, bw, gamma, beta, out, N);
    }
}